// Round 1
// baseline (959.164 us; speedup 1.0000x reference)
//
#include <hip/hip_runtime.h>
#include <math.h>

// Problem constants
#define N_B 32
#define L_S 4096
#define D_M 768
#define H_N 12

// ws layout (float offsets). [0, ZERO_N) is zeroed by one memset per call.
#define ZO_QH    0          // 768 (+pad)
#define ZO_O     1024       // [32][768]
#define ZO_XA    25600      // [32][768]
#define ZO_H1P   50176      // [32][3072]
#define ZO_MACC  148480     // [32][768]
#define ZERO_N   173056
#define NZ_QK    173056     // [12][768] h-major
#define NZ_QB    182272     // [12] (pad 64)
#define NZ_SM    182336     // [384] per-(n,h) max
#define NZ_SI    182720     // [384] per-(n,h) 1/sum
#define NZ_ATTN  183104     // [32*12][4096] RAW logits
#define NZ_XBP   1755968    // [8 lc][32 n][12 h][768 d] partial weighted sums
#define NZ_Y     4115264    // [32][768]

// ---------------------------------------------------------------------------
// qh[i] = 0.125*(probe @ wq + bq)[i]. Split-k: grid (3 itile, 16 ksplit).
__global__ __launch_bounds__(256) void qh_kernel(
    const float* __restrict__ probe, const float* __restrict__ wq,
    const float* __restrict__ bq, float* __restrict__ qh) {
    int i = blockIdx.x * 256 + threadIdx.x;
    int d0 = blockIdx.y * 48;
    float acc = 0.f;
    for (int dd = 0; dd < 48; ++dd)
        acc += probe[d0 + dd] * wq[(size_t)(d0 + dd) * 768 + i];
    acc *= 0.125f;
    if (blockIdx.y == 0) acc += 0.125f * bq[i];
    atomicAdd(&qh[i], acc);
}

// qk[h][d] = sum_e qh[h*64+e]*wk[d*768+h*64+e]; qb[h] = qh_h . bk_h.
__global__ __launch_bounds__(256) void qk_kernel(
    const float* __restrict__ qh, const float* __restrict__ wk,
    const float* __restrict__ bk, float* __restrict__ qk,
    float* __restrict__ qb) {
    int h = blockIdx.x, dt = blockIdx.y, t = threadIdx.x;
    int d = dt * 256 + t;
    const float4* wk4 = (const float4*)(wk + (size_t)d * 768 + h * 64);
    const float4* qh4 = (const float4*)(qh + h * 64);
    float acc = 0.f;
    #pragma unroll
    for (int e4 = 0; e4 < 16; ++e4) {
        float4 w = wk4[e4], q = qh4[e4];
        acc += w.x * q.x + w.y * q.y + w.z * q.z + w.w * q.w;
    }
    qk[h * 768 + d] = acc;
    if (dt == 0 && t < 64) {
        float v = qh[h * 64 + t] * bk[h * 64 + t];
        #pragma unroll
        for (int off = 32; off > 0; off >>= 1) v += __shfl_xor(v, off);
        if (t == 0) qb[h] = v;
    }
}

// ---------------------------------------------------------------------------
// logits (raw, pre-softmax). 16 lanes per row: each instruction reads 4 rows
// x 256B fully-consumed segments -> no L1 line-reuse dependence. qk staged in
// LDS (36KB), wave-uniform per 16-group -> broadcast. Butterfly reduce over
// the 16-lane group, lanes 0..11 scatter-store the 12 head logits.
__global__ __launch_bounds__(256) void logits_kernel(
    const float* __restrict__ x, const float* __restrict__ qk,
    const float* __restrict__ qb, float* __restrict__ attn) {
    __shared__ __align__(16) float qk_s[12 * 768];
    int t = threadIdx.x;
    for (int i = t; i < 12 * 192; i += 256)
        ((float4*)qk_s)[i] = ((const float4*)qk)[i];
    __syncthreads();
    int lane = t & 63, w = t >> 6;
    int l4 = lane & 15, g = lane >> 4;
    int wid = blockIdx.x * 4 + w;            // 0..2047, owns 64 rows
    const float4* qs4 = (const float4*)qk_s;
    for (int pass = 0; pass < 16; ++pass) {
        int r = wid * 64 + pass * 4 + g;     // global row 0..131071
        const float4* xr = (const float4*)(x + (size_t)r * 768);
        float acc[12];
        #pragma unroll
        for (int h = 0; h < 12; ++h) acc[h] = 0.f;
        #pragma unroll
        for (int it = 0; it < 12; ++it) {
            float4 xv = xr[it * 16 + l4];
            #pragma unroll
            for (int h = 0; h < 12; ++h) {
                float4 qv = qs4[h * 192 + it * 16 + l4];
                acc[h] += xv.x * qv.x + xv.y * qv.y + xv.z * qv.z + xv.w * qv.w;
            }
        }
        #pragma unroll
        for (int h = 0; h < 12; ++h) {
            #pragma unroll
            for (int off = 1; off < 16; off <<= 1)
                acc[h] += __shfl_xor(acc[h], off);
        }
        if (l4 < 12) {
            float v = 0.f;
            #pragma unroll
            for (int h = 0; h < 12; ++h) if (l4 == h) v = acc[h];
            int n = r >> 12, l = r & 4095;
            attn[((size_t)(n * 12 + l4)) * 4096 + l] = v + qb[l4];
        }
    }
}

// ---------------------------------------------------------------------------
// softmax stats only: m = max_l, si = 1/sum_l exp(v-m). One block per (n,h).
// Normalization is applied downstream in xbar (softmax is linear wrt PV sum).
__global__ __launch_bounds__(256) void stats_kernel(
    const float* __restrict__ attn, float* __restrict__ sm,
    float* __restrict__ si) {
    const float* p = attn + (size_t)blockIdx.x * 4096;
    int tid = threadIdx.x;
    __shared__ float red[4];
    float v[16];
    #pragma unroll
    for (int k = 0; k < 16; ++k) v[k] = p[tid + 256 * k];
    float m = -1e30f;
    #pragma unroll
    for (int k = 0; k < 16; ++k) m = fmaxf(m, v[k]);
    #pragma unroll
    for (int off = 32; off > 0; off >>= 1) m = fmaxf(m, __shfl_xor(m, off));
    int wave = tid >> 6;
    if ((tid & 63) == 0) red[wave] = m;
    __syncthreads();
    m = fmaxf(fmaxf(red[0], red[1]), fmaxf(red[2], red[3]));
    float s = 0.f;
    #pragma unroll
    for (int k = 0; k < 16; ++k) s += __expf(v[k] - m);
    #pragma unroll
    for (int off = 32; off > 0; off >>= 1) s += __shfl_xor(s, off);
    __syncthreads();
    if ((tid & 63) == 0) red[wave] = s;
    __syncthreads();
    s = red[0] + red[1] + red[2] + red[3];
    if (tid == 0) { sm[blockIdx.x] = m; si[blockIdx.x] = 1.f / s; }
}

// ---------------------------------------------------------------------------
// xbar partials: xbp[lc][n][h][d] = sum_{l in chunk} softmax_w * x[n,l,d].
// Grid (8 lc, 3 dt, 32 n). Waves split the 512-l chunk (128 l each, all 12
// heads) -> each 1KB x segment loaded once per block, not 4x. exp applied
// during attn staging; 1/sum applied in epilogue. Cross-wave reduce in LDS,
// plain stores (no atomics).
#define FMA4(A, S, XV) { A.x += (S)*(XV).x; A.y += (S)*(XV).y; \
                         A.z += (S)*(XV).z; A.w += (S)*(XV).w; }
__global__ __launch_bounds__(256) void xbar_kernel(
    const float* __restrict__ x, const float* __restrict__ attn,
    const float* __restrict__ sm, const float* __restrict__ si,
    float* __restrict__ xbp) {
    int lc = blockIdx.x, dt = blockIdx.y, n = blockIdx.z;
    __shared__ __align__(16) float at_s[512 * 12];      // 24KB, [l][h]
    __shared__ __align__(16) float red_s[2 * 12 * 256]; // 24KB
    int t = threadIdx.x;
    for (int i = t; i < 512 * 12; i += 256) {
        int h = i >> 9, l = i & 511;
        float raw = attn[((size_t)(n * 12 + h)) * 4096 + lc * 512 + l];
        at_s[l * 12 + h] = __expf(raw - sm[n * 12 + h]);
    }
    __syncthreads();
    int lane = t & 63, w = t >> 6;
    const float4* x4 = (const float4*)x;
    const float4* at4 = (const float4*)at_s;
    size_t base = ((size_t)n * 4096 + lc * 512 + w * 128) * 192 + dt * 64 + lane;
    int lb = w * 128 * 3;
    float4 a[12];
    #pragma unroll
    for (int h = 0; h < 12; ++h) a[h] = make_float4(0.f, 0.f, 0.f, 0.f);
    for (int l = 0; l < 128; ++l) {
        float4 xv = x4[base + (size_t)l * 192];
        float4 w0 = at4[lb + l * 3];
        float4 w1 = at4[lb + l * 3 + 1];
        float4 w2 = at4[lb + l * 3 + 2];
        FMA4(a[0], w0.x, xv) FMA4(a[1], w0.y, xv) FMA4(a[2], w0.z, xv) FMA4(a[3], w0.w, xv)
        FMA4(a[4], w1.x, xv) FMA4(a[5], w1.y, xv) FMA4(a[6], w1.z, xv) FMA4(a[7], w1.w, xv)
        FMA4(a[8], w2.x, xv) FMA4(a[9], w2.y, xv) FMA4(a[10], w2.z, xv) FMA4(a[11], w2.w, xv)
    }
    // reduce waves {2,3} -> {0,1} -> {1} -> {0}
    if (w >= 2) {
        #pragma unroll
        for (int h = 0; h < 12; ++h)
            *(float4*)&red_s[((w - 2) * 12 + h) * 256 + lane * 4] = a[h];
    }
    __syncthreads();
    if (w < 2) {
        #pragma unroll
        for (int h = 0; h < 12; ++h) {
            float4 r = *(float4*)&red_s[(w * 12 + h) * 256 + lane * 4];
            a[h].x += r.x; a[h].y += r.y; a[h].z += r.z; a[h].w += r.w;
        }
    }
    __syncthreads();
    if (w == 1) {
        #pragma unroll
        for (int h = 0; h < 12; ++h)
            *(float4*)&red_s[h * 256 + lane * 4] = a[h];
    }
    __syncthreads();
    if (w == 0) {
        #pragma unroll
        for (int h = 0; h < 12; ++h) {
            float4 r = *(float4*)&red_s[h * 256 + lane * 4];
            float sc = si[n * 12 + h];
            r.x = (a[h].x + r.x) * sc; r.y = (a[h].y + r.y) * sc;
            r.z = (a[h].z + r.z) * sc; r.w = (a[h].w + r.w) * sc;
            *(float4*)&xbp[(((size_t)lc * 32 + n) * 12 + h) * 768 + dt * 256 + lane * 4] = r;
        }
    }
}

// ---------------------------------------------------------------------------
// o[n][h*64+e] = sum_d xbar[n,h,d]*wv[d,h,e] (+bv at k0). Grid (12 h, 8 k).
// xbar reconstructed by summing the 8 lc partials during staging.
__global__ __launch_bounds__(256) void oproj_kernel(
    const float* __restrict__ xbp, const float* __restrict__ wv,
    const float* __restrict__ bv, float* __restrict__ o) {
    int h = blockIdx.x, kk = blockIdx.y, t = threadIdx.x;
    int d0 = kk * 96;
    __shared__ __align__(16) float wv_s[96 * 64];
    __shared__ __align__(16) float xb_s[96 * 32];
    for (int i = t; i < 96 * 64; i += 256) {
        int d = i >> 6, e = i & 63;
        wv_s[i] = wv[(size_t)(d0 + d) * 768 + h * 64 + e];
    }
    for (int i = t; i < 96 * 32; i += 256) {
        int d = i >> 5, nn = i & 31;
        float s = 0.f;
        #pragma unroll
        for (int lcc = 0; lcc < 8; ++lcc)
            s += xbp[(((size_t)lcc * 32 + nn) * 12 + h) * 768 + d0 + d];
        xb_s[i] = s;
    }
    __syncthreads();
    int e = t & 63, ng = t >> 6;
    float acc[8] = {0, 0, 0, 0, 0, 0, 0, 0};
    for (int d = 0; d < 96; ++d) {
        float wvv = wv_s[d * 64 + e];
        const float4* xb4 = (const float4*)&xb_s[d * 32 + ng * 8];
        float4 p0 = xb4[0], p1 = xb4[1];
        acc[0] += p0.x * wvv; acc[1] += p0.y * wvv; acc[2] += p0.z * wvv; acc[3] += p0.w * wvv;
        acc[4] += p1.x * wvv; acc[5] += p1.y * wvv; acc[6] += p1.z * wvv; acc[7] += p1.w * wvv;
    }
    float bvv = (kk == 0) ? bv[h * 64 + e] : 0.f;
    #pragma unroll
    for (int k = 0; k < 8; ++k)
        atomicAdd(&o[(size_t)(ng * 8 + k) * 768 + h * 64 + e], acc[k] + bvv);
}

// xa[n][d] = sum_i o[n][i]*wo[i*768+d] (+bo at k0). Grid (3 dtile, 8 k).
__global__ __launch_bounds__(256) void xaproj_kernel(
    const float* __restrict__ o, const float* __restrict__ wo,
    const float* __restrict__ bo, float* __restrict__ xa) {
    int dt = blockIdx.x, kk = blockIdx.y, t = threadIdx.x;
    int i0 = kk * 96;
    __shared__ __align__(16) float o_s[96 * 32];
    for (int idx = t; idx < 96 * 32; idx += 256) {
        int i = idx >> 5, nn = idx & 31;
        o_s[idx] = o[(size_t)nn * 768 + i0 + i];
    }
    __syncthreads();
    int d = dt * 256 + t;
    float acc[32];
    #pragma unroll
    for (int nn = 0; nn < 32; ++nn) acc[nn] = 0.f;
    for (int i = 0; i < 96; ++i) {
        float w = wo[(size_t)(i0 + i) * 768 + d];
        const float4* o4 = (const float4*)&o_s[i * 32];
        #pragma unroll
        for (int q = 0; q < 8; ++q) {
            float4 f = o4[q];
            acc[q * 4 + 0] += f.x * w; acc[q * 4 + 1] += f.y * w;
            acc[q * 4 + 2] += f.z * w; acc[q * 4 + 3] += f.w * w;
        }
    }
    float bov = (kk == 0) ? bo[d] : 0.f;
    #pragma unroll
    for (int nn = 0; nn < 32; ++nn)
        atomicAdd(&xa[(size_t)nn * 768 + d], acc[nn] + bov);
}

// ---------------------------------------------------------------------------
// y = LayerNorm(xa). One block per n.
__global__ __launch_bounds__(256) void ln_kernel(
    const float* __restrict__ xa, const float* __restrict__ ln_scale,
    const float* __restrict__ ln_bias, float* __restrict__ y) {
    int n = blockIdx.x, tid = threadIdx.x;
    __shared__ float xs[768];
    __shared__ float red[4];
    for (int i = tid; i < 768; i += 256) xs[i] = xa[(size_t)n * 768 + i];
    __syncthreads();
    float lsum = 0.f;
    for (int i = tid; i < 768; i += 256) lsum += xs[i];
    #pragma unroll
    for (int off = 32; off > 0; off >>= 1) lsum += __shfl_xor(lsum, off);
    int wave = tid >> 6;
    if ((tid & 63) == 0) red[wave] = lsum;
    __syncthreads();
    float mu = (red[0] + red[1] + red[2] + red[3]) * (1.f / 768.f);
    __syncthreads();
    float lsq = 0.f;
    for (int i = tid; i < 768; i += 256) { float c = xs[i] - mu; lsq += c * c; }
    #pragma unroll
    for (int off = 32; off > 0; off >>= 1) lsq += __shfl_xor(lsq, off);
    if ((tid & 63) == 0) red[wave] = lsq;
    __syncthreads();
    float var = (red[0] + red[1] + red[2] + red[3]) * (1.f / 768.f);
    float rs = rsqrtf(var + 1e-6f);
    for (int i = tid; i < 768; i += 256)
        y[(size_t)n * 768 + i] = (xs[i] - mu) * rs * ln_scale[i] + ln_bias[i];
}

// ---------------------------------------------------------------------------
// h1pre[n][j] += sum_d y[n][d]*w1[d][j]. Grid (12 jtile, 16 k).
__global__ __launch_bounds__(256) void mlp1_kernel(
    const float* __restrict__ y, const float* __restrict__ w1,
    float* __restrict__ h1p) {
    int jt = blockIdx.x, kk = blockIdx.y, t = threadIdx.x;
    int d0 = kk * 48;
    __shared__ __align__(16) float y_s[48 * 32];
    for (int idx = t; idx < 48 * 32; idx += 256) {
        int d = idx >> 5, nn = idx & 31;
        y_s[idx] = y[(size_t)nn * 768 + d0 + d];
    }
    __syncthreads();
    int j = jt * 256 + t;
    float acc[32];
    #pragma unroll
    for (int nn = 0; nn < 32; ++nn) acc[nn] = 0.f;
    for (int d = 0; d < 48; ++d) {
        float w = w1[(size_t)(d0 + d) * 3072 + j];
        const float4* y4 = (const float4*)&y_s[d * 32];
        #pragma unroll
        for (int q = 0; q < 8; ++q) {
            float4 f = y4[q];
            acc[q * 4 + 0] += f.x * w; acc[q * 4 + 1] += f.y * w;
            acc[q * 4 + 2] += f.z * w; acc[q * 4 + 3] += f.w * w;
        }
    }
    #pragma unroll
    for (int nn = 0; nn < 32; ++nn)
        atomicAdd(&h1p[(size_t)nn * 3072 + j], acc[nn]);
}

// macc[n][d] += sum_j gelu(h1p+b1)[n][j]*w2[j][d]. Grid (3 dtile, 64 k).
// gelu fused into LDS staging (recomputed 3x across dt -- negligible).
__global__ __launch_bounds__(256) void mlp2_kernel(
    const float* __restrict__ h1p, const float* __restrict__ b1,
    const float* __restrict__ w2, float* __restrict__ macc) {
    int dt = blockIdx.x, kk = blockIdx.y, t = threadIdx.x;
    int j0 = kk * 48;
    __shared__ __align__(16) float h_s[48 * 32];
    for (int idx = t; idx < 48 * 32; idx += 256) {
        int j = idx >> 5, nn = idx & 31;
        float tv = h1p[(size_t)nn * 3072 + j0 + j] + b1[j0 + j];
        float u = 0.7978845608028654f * (tv + 0.044715f * tv * tv * tv);
        h_s[idx] = 0.5f * tv * (1.f + tanhf(u));
    }
    __syncthreads();
    int d = dt * 256 + t;
    float acc[32];
    #pragma unroll
    for (int nn = 0; nn < 32; ++nn) acc[nn] = 0.f;
    for (int j = 0; j < 48; ++j) {
        float w = w2[(size_t)(j0 + j) * 768 + d];
        const float4* h4 = (const float4*)&h_s[j * 32];
        #pragma unroll
        for (int q = 0; q < 8; ++q) {
            float4 f = h4[q];
            acc[q * 4 + 0] += f.x * w; acc[q * 4 + 1] += f.y * w;
            acc[q * 4 + 2] += f.z * w; acc[q * 4 + 3] += f.w * w;
        }
    }
    #pragma unroll
    for (int nn = 0; nn < 32; ++nn)
        atomicAdd(&macc[(size_t)nn * 768 + d], acc[nn]);
}

// out = xa + b2 + macc. Grid 32 n.
__global__ __launch_bounds__(256) void final_kernel(
    const float* __restrict__ xa, const float* __restrict__ b2,
    const float* __restrict__ macc, float* __restrict__ out) {
    int n = blockIdx.x, t = threadIdx.x;
    for (int i = t; i < 768; i += 256)
        out[(size_t)n * 768 + i] = xa[(size_t)n * 768 + i] + b2[i] + macc[(size_t)n * 768 + i];
}

// ---------------------------------------------------------------------------
extern "C" void kernel_launch(void* const* d_in, const int* in_sizes, int n_in,
                              void* d_out, int out_size, void* d_ws, size_t ws_size,
                              hipStream_t stream) {
    const float* x        = (const float*)d_in[0];
    const float* probe    = (const float*)d_in[1];
    const float* wq       = (const float*)d_in[2];
    const float* bq       = (const float*)d_in[3];
    const float* wk       = (const float*)d_in[4];
    const float* bk       = (const float*)d_in[5];
    const float* wv       = (const float*)d_in[6];
    const float* bv       = (const float*)d_in[7];
    const float* wo       = (const float*)d_in[8];
    const float* bo       = (const float*)d_in[9];
    const float* ln_scale = (const float*)d_in[10];
    const float* ln_bias  = (const float*)d_in[11];
    const float* w1       = (const float*)d_in[12];
    const float* b1       = (const float*)d_in[13];
    const float* w2       = (const float*)d_in[14];
    const float* b2       = (const float*)d_in[15];
    float* out = (float*)d_out;
    float* ws  = (float*)d_ws;

    float* qh   = ws + ZO_QH;
    float* o    = ws + ZO_O;
    float* xa   = ws + ZO_XA;
    float* h1p  = ws + ZO_H1P;
    float* macc = ws + ZO_MACC;
    float* qk   = ws + NZ_QK;
    float* qb   = ws + NZ_QB;
    float* sm   = ws + NZ_SM;
    float* si   = ws + NZ_SI;
    float* attn = ws + NZ_ATTN;
    float* xbp  = ws + NZ_XBP;
    float* y    = ws + NZ_Y;

    hipMemsetAsync(ws, 0, (size_t)ZERO_N * sizeof(float), stream);
    qh_kernel<<<dim3(3, 16), 256, 0, stream>>>(probe, wq, bq, qh);
    qk_kernel<<<dim3(12, 3), 256, 0, stream>>>(qh, wk, bk, qk, qb);
    logits_kernel<<<512, 256, 0, stream>>>(x, qk, qb, attn);
    stats_kernel<<<N_B * H_N, 256, 0, stream>>>(attn, sm, si);
    xbar_kernel<<<dim3(8, 3, 32), 256, 0, stream>>>(x, attn, sm, si, xbp);
    oproj_kernel<<<dim3(12, 8), 256, 0, stream>>>(xbp, wv, bv, o);
    xaproj_kernel<<<dim3(3, 8), 256, 0, stream>>>(o, wo, bo, xa);
    ln_kernel<<<N_B, 256, 0, stream>>>(xa, ln_scale, ln_bias, y);
    mlp1_kernel<<<dim3(12, 16), 256, 0, stream>>>(y, w1, h1p);
    mlp2_kernel<<<dim3(3, 64), 256, 0, stream>>>(h1p, b1, w2, macc);
    final_kernel<<<N_B, 256, 0, stream>>>(xa, b2, macc, out);
}

// Round 3
// 759.431 us; speedup vs baseline: 1.2630x; 1.2630x over previous
//
#include <hip/hip_runtime.h>
#include <math.h>

// Problem constants
#define N_B 32
#define L_S 4096
#define D_M 768
#define H_N 12
#define NCH 16          // l-chunks (256 rows each)

// ws layout (float offsets). [0, ZERO_N) is zeroed by one memset per call.
#define ZO_QH    0          // 768 (+pad)
#define ZO_O     1024       // [32][768]
#define ZO_XA    25600      // [32][768]
#define ZO_H1P   50176      // [32][3072]
#define ZO_MACC  148480     // [32][768]
#define ZERO_N   173056
#define NZ_QK    173056     // [12][768] h-major
#define NZ_QB    182272     // [12] (pad 64)
#define NZ_MLC   182336     // [32*12][16] per-(n,h,lc) running max
#define NZ_SLC   188480     // [32*12][16] per-(n,h,lc) running sum
#define NZ_SCL   194624     // [16][32][12] merge scale factors
#define NZ_XBP   200768     // [16 lc][32 n][12 h][768 d] unnormalized partials
#define NZ_Y     4919360    // [32][768]

// ---------------------------------------------------------------------------
// qh[i] = 0.125*(probe @ wq + bq)[i]. Split-k: grid (3 itile, 16 ksplit).
__global__ __launch_bounds__(256) void qh_kernel(
    const float* __restrict__ probe, const float* __restrict__ wq,
    const float* __restrict__ bq, float* __restrict__ qh) {
    int i = blockIdx.x * 256 + threadIdx.x;
    int d0 = blockIdx.y * 48;
    float acc = 0.f;
    for (int dd = 0; dd < 48; ++dd)
        acc += probe[d0 + dd] * wq[(size_t)(d0 + dd) * 768 + i];
    acc *= 0.125f;
    if (blockIdx.y == 0) acc += 0.125f * bq[i];
    atomicAdd(&qh[i], acc);
}

// qk[h][d] = sum_e qh[h*64+e]*wk[d*768+h*64+e]; qb[h] = qh_h . bk_h.
__global__ __launch_bounds__(256) void qk_kernel(
    const float* __restrict__ qh, const float* __restrict__ wk,
    const float* __restrict__ bk, float* __restrict__ qk,
    float* __restrict__ qb) {
    int h = blockIdx.x, dt = blockIdx.y, t = threadIdx.x;
    int d = dt * 256 + t;
    const float4* wk4 = (const float4*)(wk + (size_t)d * 768 + h * 64);
    const float4* qh4 = (const float4*)(qh + h * 64);
    float acc = 0.f;
    #pragma unroll
    for (int e4 = 0; e4 < 16; ++e4) {
        float4 w = wk4[e4], q = qh4[e4];
        acc += w.x * q.x + w.y * q.y + w.z * q.z + w.w * q.w;
    }
    qk[h * 768 + d] = acc;
    if (dt == 0 && t < 64) {
        float v = qh[h * 64 + t] * bk[h * 64 + t];
        #pragma unroll
        for (int off = 32; off > 0; off >>= 1) v += __shfl_xor(v, off);
        if (t == 0) qb[h] = v;
    }
}

// ---------------------------------------------------------------------------
// Fused flash-style attention inner phase. Block = (lc, n): 256 rows of x,
// streamed ONCE through a double-buffered 4-row LDS tile. Per subtile:
//   phase1: 48 dots (4r x 12h), thread=(r,h,quarter) with d-interleaved
//           quarters, 2-shuffle combine -> lg_s.
//   bookkeeping (t<12): online max/sum per head, tile weights w_s, rescale sc_s.
//   phase2: all 256 threads own 3 d-cols; acc[12][3] += w * x (unnormalized).
// Output: xbp[lc][n][h][768] partials + per-chunk (m, s). Normalization and
// cross-chunk merge are exact via softmax linearity (merge_kernel -> oproj).
// LDS = 62.5 KB (qk padded to 772 to break the 768-float bank alignment).
__global__ __launch_bounds__(256) void attn_fused(
    const float* __restrict__ x, const float* __restrict__ qk,
    const float* __restrict__ qb, float* __restrict__ xbp,
    float* __restrict__ mlc, float* __restrict__ slc) {
    __shared__ __align__(16) float qk_s[12 * 772];
    __shared__ __align__(16) float xs[2 * 4 * 772];
    __shared__ float lg_s[64], w_s[64], qb_s[16], ms_s[16], ss_s[16], sc_s[16];
    int lc = blockIdx.x, n = blockIdx.y, t = threadIdx.x;
    int lane = t & 63, w = t >> 6;
    size_t xbase = ((size_t)n * 4096 + lc * 256) * 768;

    // stage qk (padded rows), qb, init state
    for (int i = t; i < 12 * 192; i += 256) {
        int hh = i / 192, c = i % 192;
        ((float4*)&qk_s[hh * 772])[c] = ((const float4*)qk)[i];
    }
    if (t < 12) { qb_s[t] = qb[t]; ms_s[t] = -1e30f; ss_s[t] = 0.f; }
    // stage subtile 0 into buffer 0
    {
        const float4* s0 = (const float4*)(x + xbase);
        for (int j = t; j < 768; j += 256) {
            float4 v = s0[j];
            *((float4*)&xs[(j / 192) * 772 + (j % 192) * 4]) = v;
        }
    }
    float acc[12][3];
    #pragma unroll
    for (int h = 0; h < 12; ++h) { acc[h][0] = 0.f; acc[h][1] = 0.f; acc[h][2] = 0.f; }
    int q = t & 3, rh = t >> 2, h1 = rh % 12, r1 = t / 48;
    int d0 = t * 3;
    __syncthreads();

    int p = 0;
    for (int it = 0; it < 64; ++it) {
        // wave 3: stage subtile it+1 into buffer p^1 (reg staging; loads
        // issued early, latency hides under waves 0-2's phase1)
        if (w == 3 && it + 1 < 64) {
            const float4* src = (const float4*)(x + xbase + (size_t)(it + 1) * 3072);
            #pragma unroll
            for (int j = 0; j < 12; ++j) {
                int f = lane + 64 * j;
                float4 v = src[f];
                *((float4*)&xs[(p ^ 1) * 3088 + (f / 192) * 772 + (f % 192) * 4]) = v;
            }
        }
        // phase1: waves 0-2, one (r,h,quarter) each
        if (t < 192) {
            const float4* xr = (const float4*)&xs[p * 3088 + r1 * 772];
            const float4* kr = (const float4*)&qk_s[h1 * 772];
            float a = 0.f;
            #pragma unroll 8
            for (int s = 0; s < 48; ++s) {
                int idx = s * 4 + q;
                float4 xv = xr[idx], kv = kr[idx];
                a += xv.x * kv.x + xv.y * kv.y + xv.z * kv.z + xv.w * kv.w;
            }
            a += __shfl_xor(a, 1);
            a += __shfl_xor(a, 2);
            if (q == 0) lg_s[r1 * 16 + h1] = a + qb_s[h1];
        }
        __syncthreads();
        // bookkeeping: thread h<12, online softmax state update
        if (t < 12) {
            float l0 = lg_s[0 * 16 + t], l1 = lg_s[1 * 16 + t];
            float l2 = lg_s[2 * 16 + t], l3 = lg_s[3 * 16 + t];
            float mt = fmaxf(fmaxf(l0, l1), fmaxf(l2, l3));
            float mo = ms_s[t];
            float mn = fmaxf(mo, mt);
            float sc = __expf(mo - mn);
            float e0 = __expf(l0 - mn), e1 = __expf(l1 - mn);
            float e2 = __expf(l2 - mn), e3 = __expf(l3 - mn);
            w_s[0 * 16 + t] = e0; w_s[1 * 16 + t] = e1;
            w_s[2 * 16 + t] = e2; w_s[3 * 16 + t] = e3;
            ms_s[t] = mn;
            ss_s[t] = ss_s[t] * sc + (e0 + e1 + e2 + e3);
            sc_s[t] = sc;
        }
        __syncthreads();
        // phase2: rescale + accumulate (all 256 threads, 3 d-cols each)
        const float* xb = &xs[p * 3088];
        #pragma unroll
        for (int h = 0; h < 12; ++h) {
            float sc = sc_s[h];
            acc[h][0] *= sc; acc[h][1] *= sc; acc[h][2] *= sc;
        }
        #pragma unroll
        for (int l = 0; l < 4; ++l) {
            float x0 = xb[l * 772 + d0], x1 = xb[l * 772 + d0 + 1], x2 = xb[l * 772 + d0 + 2];
            #pragma unroll
            for (int h = 0; h < 12; ++h) {
                float wv = w_s[l * 16 + h];
                acc[h][0] += wv * x0; acc[h][1] += wv * x1; acc[h][2] += wv * x2;
            }
        }
        __syncthreads();   // all reads of buf p done; stage (it+1) complete
        p ^= 1;
    }
    // write partials + per-chunk stats
    size_t ob = ((size_t)(lc * 32 + n)) * 12 * 768;
    #pragma unroll
    for (int h = 0; h < 12; ++h) {
        xbp[ob + h * 768 + d0 + 0] = acc[h][0];
        xbp[ob + h * 768 + d0 + 1] = acc[h][1];
        xbp[ob + h * 768 + d0 + 2] = acc[h][2];
    }
    if (t < 12) {
        mlc[(n * 12 + t) * 16 + lc] = ms_s[t];
        slc[(n * 12 + t) * 16 + lc] = ss_s[t];
    }
}

// merge: scl[lc][n][h] = exp(m_lc - M) / sum_lc s_lc*exp(m_lc - M).
__global__ __launch_bounds__(256) void merge_kernel(
    const float* __restrict__ mlc, const float* __restrict__ slc,
    float* __restrict__ scl) {
    int t = threadIdx.x;
    for (int pr = t; pr < 384; pr += 256) {     // pr = n*12+h
        float M = -1e30f;
        #pragma unroll
        for (int c = 0; c < 16; ++c) M = fmaxf(M, mlc[pr * 16 + c]);
        float e[16];
        float T = 0.f;
        #pragma unroll
        for (int c = 0; c < 16; ++c) {
            e[c] = __expf(mlc[pr * 16 + c] - M);
            T += slc[pr * 16 + c] * e[c];
        }
        float inv = 1.f / T;
        int n = pr / 12, h = pr % 12;
        #pragma unroll
        for (int c = 0; c < 16; ++c)
            scl[(c * 32 + n) * 12 + h] = e[c] * inv;
    }
}

// ---------------------------------------------------------------------------
// o[n][h*64+e] = sum_d xbar[n,h,d]*wv[d,h,e] (+bv at k0). Grid (12 h, 8 k).
// xbar reconstructed by scale-summing the 16 chunk partials during staging.
__global__ __launch_bounds__(256) void oproj_kernel(
    const float* __restrict__ xbp, const float* __restrict__ scl,
    const float* __restrict__ wv, const float* __restrict__ bv,
    float* __restrict__ o) {
    int h = blockIdx.x, kk = blockIdx.y, t = threadIdx.x;
    int d0 = kk * 96;
    __shared__ __align__(16) float wv_s[96 * 64];
    __shared__ __align__(16) float xb_s[96 * 32];
    for (int i = t; i < 96 * 64; i += 256) {
        int d = i >> 6, e = i & 63;
        wv_s[i] = wv[(size_t)(d0 + d) * 768 + h * 64 + e];
    }
    for (int i = t; i < 96 * 32; i += 256) {
        int d = i >> 5, nn = i & 31;
        float s = 0.f;
        #pragma unroll
        for (int lcc = 0; lcc < 16; ++lcc)
            s += xbp[(((size_t)lcc * 32 + nn) * 12 + h) * 768 + d0 + d]
               * scl[(lcc * 32 + nn) * 12 + h];
        xb_s[i] = s;
    }
    __syncthreads();
    int e = t & 63, ng = t >> 6;
    float acc[8] = {0, 0, 0, 0, 0, 0, 0, 0};
    for (int d = 0; d < 96; ++d) {
        float wvv = wv_s[d * 64 + e];
        const float4* xb4 = (const float4*)&xb_s[d * 32 + ng * 8];
        float4 p0 = xb4[0], p1 = xb4[1];
        acc[0] += p0.x * wvv; acc[1] += p0.y * wvv; acc[2] += p0.z * wvv; acc[3] += p0.w * wvv;
        acc[4] += p1.x * wvv; acc[5] += p1.y * wvv; acc[6] += p1.z * wvv; acc[7] += p1.w * wvv;
    }
    float bvv = (kk == 0) ? bv[h * 64 + e] : 0.f;
    #pragma unroll
    for (int k = 0; k < 8; ++k)
        atomicAdd(&o[(size_t)(ng * 8 + k) * 768 + h * 64 + e], acc[k] + bvv);
}

// xa[n][d] = sum_i o[n][i]*wo[i*768+d] (+bo at k0). Grid (3 dtile, 8 k).
__global__ __launch_bounds__(256) void xaproj_kernel(
    const float* __restrict__ o, const float* __restrict__ wo,
    const float* __restrict__ bo, float* __restrict__ xa) {
    int dt = blockIdx.x, kk = blockIdx.y, t = threadIdx.x;
    int i0 = kk * 96;
    __shared__ __align__(16) float o_s[96 * 32];
    for (int idx = t; idx < 96 * 32; idx += 256) {
        int i = idx >> 5, nn = idx & 31;
        o_s[idx] = o[(size_t)nn * 768 + i0 + i];
    }
    __syncthreads();
    int d = dt * 256 + t;
    float acc[32];
    #pragma unroll
    for (int nn = 0; nn < 32; ++nn) acc[nn] = 0.f;
    for (int i = 0; i < 96; ++i) {
        float w = wo[(size_t)(i0 + i) * 768 + d];
        const float4* o4 = (const float4*)&o_s[i * 32];
        #pragma unroll
        for (int qq = 0; qq < 8; ++qq) {
            float4 f = o4[qq];
            acc[qq * 4 + 0] += f.x * w; acc[qq * 4 + 1] += f.y * w;
            acc[qq * 4 + 2] += f.z * w; acc[qq * 4 + 3] += f.w * w;
        }
    }
    float bov = (kk == 0) ? bo[d] : 0.f;
    #pragma unroll
    for (int nn = 0; nn < 32; ++nn)
        atomicAdd(&xa[(size_t)nn * 768 + d], acc[nn] + bov);
}

// ---------------------------------------------------------------------------
// y = LayerNorm(xa). One block per n.
__global__ __launch_bounds__(256) void ln_kernel(
    const float* __restrict__ xa, const float* __restrict__ ln_scale,
    const float* __restrict__ ln_bias, float* __restrict__ y) {
    int n = blockIdx.x, tid = threadIdx.x;
    __shared__ float xs[768];
    __shared__ float red[4];
    for (int i = tid; i < 768; i += 256) xs[i] = xa[(size_t)n * 768 + i];
    __syncthreads();
    float lsum = 0.f;
    for (int i = tid; i < 768; i += 256) lsum += xs[i];
    #pragma unroll
    for (int off = 32; off > 0; off >>= 1) lsum += __shfl_xor(lsum, off);
    int wave = tid >> 6;
    if ((tid & 63) == 0) red[wave] = lsum;
    __syncthreads();
    float mu = (red[0] + red[1] + red[2] + red[3]) * (1.f / 768.f);
    __syncthreads();
    float lsq = 0.f;
    for (int i = tid; i < 768; i += 256) { float c = xs[i] - mu; lsq += c * c; }
    #pragma unroll
    for (int off = 32; off > 0; off >>= 1) lsq += __shfl_xor(lsq, off);
    if ((tid & 63) == 0) red[wave] = lsq;
    __syncthreads();
    float var = (red[0] + red[1] + red[2] + red[3]) * (1.f / 768.f);
    float rs = rsqrtf(var + 1e-6f);
    for (int i = tid; i < 768; i += 256)
        y[(size_t)n * 768 + i] = (xs[i] - mu) * rs * ln_scale[i] + ln_bias[i];
}

// ---------------------------------------------------------------------------
// h1pre[n][j] += sum_d y[n][d]*w1[d][j]. Grid (12 jtile, 16 k).
__global__ __launch_bounds__(256) void mlp1_kernel(
    const float* __restrict__ y, const float* __restrict__ w1,
    float* __restrict__ h1p) {
    int jt = blockIdx.x, kk = blockIdx.y, t = threadIdx.x;
    int d0 = kk * 48;
    __shared__ __align__(16) float y_s[48 * 32];
    for (int idx = t; idx < 48 * 32; idx += 256) {
        int d = idx >> 5, nn = idx & 31;
        y_s[idx] = y[(size_t)nn * 768 + d0 + d];
    }
    __syncthreads();
    int j = jt * 256 + t;
    float acc[32];
    #pragma unroll
    for (int nn = 0; nn < 32; ++nn) acc[nn] = 0.f;
    for (int d = 0; d < 48; ++d) {
        float w = w1[(size_t)(d0 + d) * 3072 + j];
        const float4* y4 = (const float4*)&y_s[d * 32];
        #pragma unroll
        for (int qq = 0; qq < 8; ++qq) {
            float4 f = y4[qq];
            acc[qq * 4 + 0] += f.x * w; acc[qq * 4 + 1] += f.y * w;
            acc[qq * 4 + 2] += f.z * w; acc[qq * 4 + 3] += f.w * w;
        }
    }
    #pragma unroll
    for (int nn = 0; nn < 32; ++nn)
        atomicAdd(&h1p[(size_t)nn * 3072 + j], acc[nn]);
}

// macc[n][d] += sum_j gelu(h1p+b1)[n][j]*w2[j][d]. Grid (3 dtile, 64 k).
// gelu fused into LDS staging (recomputed 3x across dt -- negligible).
__global__ __launch_bounds__(256) void mlp2_kernel(
    const float* __restrict__ h1p, const float* __restrict__ b1,
    const float* __restrict__ w2, float* __restrict__ macc) {
    int dt = blockIdx.x, kk = blockIdx.y, t = threadIdx.x;
    int j0 = kk * 48;
    __shared__ __align__(16) float h_s[48 * 32];
    for (int idx = t; idx < 48 * 32; idx += 256) {
        int j = idx >> 5, nn = idx & 31;
        float tv = h1p[(size_t)nn * 3072 + j0 + j] + b1[j0 + j];
        float u = 0.7978845608028654f * (tv + 0.044715f * tv * tv * tv);
        h_s[idx] = 0.5f * tv * (1.f + tanhf(u));
    }
    __syncthreads();
    int d = dt * 256 + t;
    float acc[32];
    #pragma unroll
    for (int nn = 0; nn < 32; ++nn) acc[nn] = 0.f;
    for (int j = 0; j < 48; ++j) {
        float w = w2[(size_t)(j0 + j) * 768 + d];
        const float4* h4 = (const float4*)&h_s[j * 32];
        #pragma unroll
        for (int qq = 0; qq < 8; ++qq) {
            float4 f = h4[qq];
            acc[qq * 4 + 0] += f.x * w; acc[qq * 4 + 1] += f.y * w;
            acc[qq * 4 + 2] += f.z * w; acc[qq * 4 + 3] += f.w * w;
        }
    }
    #pragma unroll
    for (int nn = 0; nn < 32; ++nn)
        atomicAdd(&macc[(size_t)nn * 768 + d], acc[nn]);
}

// out = xa + b2 + macc. Grid 32 n.
__global__ __launch_bounds__(256) void final_kernel(
    const float* __restrict__ xa, const float* __restrict__ b2,
    const float* __restrict__ macc, float* __restrict__ out) {
    int n = blockIdx.x, t = threadIdx.x;
    for (int i = t; i < 768; i += 256)
        out[(size_t)n * 768 + i] = xa[(size_t)n * 768 + i] + b2[i] + macc[(size_t)n * 768 + i];
}

// ---------------------------------------------------------------------------
extern "C" void kernel_launch(void* const* d_in, const int* in_sizes, int n_in,
                              void* d_out, int out_size, void* d_ws, size_t ws_size,
                              hipStream_t stream) {
    const float* x        = (const float*)d_in[0];
    const float* probe    = (const float*)d_in[1];
    const float* wq       = (const float*)d_in[2];
    const float* bq       = (const float*)d_in[3];
    const float* wk       = (const float*)d_in[4];
    const float* bk       = (const float*)d_in[5];
    const float* wv       = (const float*)d_in[6];
    const float* bv       = (const float*)d_in[7];
    const float* wo       = (const float*)d_in[8];
    const float* bo       = (const float*)d_in[9];
    const float* ln_scale = (const float*)d_in[10];
    const float* ln_bias  = (const float*)d_in[11];
    const float* w1       = (const float*)d_in[12];
    const float* b1       = (const float*)d_in[13];
    const float* w2       = (const float*)d_in[14];
    const float* b2       = (const float*)d_in[15];
    float* out = (float*)d_out;
    float* ws  = (float*)d_ws;

    float* qh   = ws + ZO_QH;
    float* o    = ws + ZO_O;
    float* xa   = ws + ZO_XA;
    float* h1p  = ws + ZO_H1P;
    float* macc = ws + ZO_MACC;
    float* qk   = ws + NZ_QK;
    float* qb   = ws + NZ_QB;
    float* mlc  = ws + NZ_MLC;
    float* slc  = ws + NZ_SLC;
    float* scl  = ws + NZ_SCL;
    float* xbp  = ws + NZ_XBP;
    float* y    = ws + NZ_Y;

    hipMemsetAsync(ws, 0, (size_t)ZERO_N * sizeof(float), stream);
    qh_kernel<<<dim3(3, 16), 256, 0, stream>>>(probe, wq, bq, qh);
    qk_kernel<<<dim3(12, 3), 256, 0, stream>>>(qh, wk, bk, qk, qb);
    attn_fused<<<dim3(NCH, 32), 256, 0, stream>>>(x, qk, qb, xbp, mlc, slc);
    merge_kernel<<<1, 256, 0, stream>>>(mlc, slc, scl);
    oproj_kernel<<<dim3(12, 8), 256, 0, stream>>>(xbp, scl, wv, bv, o);
    xaproj_kernel<<<dim3(3, 8), 256, 0, stream>>>(o, wo, bo, xa);
    ln_kernel<<<N_B, 256, 0, stream>>>(xa, ln_scale, ln_bias, y);
    mlp1_kernel<<<dim3(12, 16), 256, 0, stream>>>(y, w1, h1p);
    mlp2_kernel<<<dim3(3, 64), 256, 0, stream>>>(h1p, b1, w2, macc);
    final_kernel<<<N_B, 256, 0, stream>>>(xa, b2, macc, out);
}